// Round 1
// baseline (228.178 us; speedup 1.0000x reference)
//
#include <hip/hip_runtime.h>
#include <math.h>

#define NLEV   16
#define TSIZE  524288
#define TMASK  524287
#define HIDDEN 64
#define NPIX   (1024*1024)

struct ResArr { float r[NLEV]; };

__global__ __launch_bounds__(256) void ngp_fused_kernel(
    const float* __restrict__ tables,
    const float* __restrict__ W1, const float* __restrict__ b1,
    const float* __restrict__ W2, const float* __restrict__ b2,
    const float* __restrict__ W3, const float* __restrict__ b3,
    float* __restrict__ out, ResArr res)
{
    const int lx = threadIdx.x & 31;
    const int ly = threadIdx.x >> 5;
    const int x  = blockIdx.x * 32 + lx;
    const int y  = blockIdx.y * 8  + ly;
    const float ux = (float)x * (1.0f / 1024.0f);
    const float uy = (float)y * (1.0f / 1024.0f);

    // ---- hash-grid encoding: 16 levels, 4 corners each ----
    float enc[2 * NLEV];
    #pragma unroll
    for (int l = 0; l < NLEV; ++l) {
        const float r  = res.r[l];
        const float sx = ux * r;
        const float sy = uy * r;
        const float fx0 = floorf(sx), fy0 = floorf(sy);
        const float fx = sx - fx0,    fy = sy - fy0;
        const uint32_t cx = (uint32_t)fx0;
        const uint32_t cy = (uint32_t)fy0;
        const uint32_t hy0 = cy * 2654435761u;
        const uint32_t hy1 = (cy + 1u) * 2654435761u;
        const uint32_t i00 = ( cx        ^ hy0) & TMASK;
        const uint32_t i10 = ((cx + 1u)  ^ hy0) & TMASK;
        const uint32_t i01 = ( cx        ^ hy1) & TMASK;
        const uint32_t i11 = ((cx + 1u)  ^ hy1) & TMASK;
        const float2* __restrict__ tab =
            (const float2*)(tables + (size_t)l * (size_t)(TSIZE * 2));
        const float2 f00 = tab[i00];
        const float2 f10 = tab[i10];
        const float2 f01 = tab[i01];
        const float2 f11 = tab[i11];
        const float w00 = (1.0f - fx) * (1.0f - fy);
        const float w10 = fx          * (1.0f - fy);
        const float w01 = (1.0f - fx) * fy;
        const float w11 = fx          * fy;
        enc[2*l+0] = w00*f00.x + w10*f10.x + w01*f01.x + w11*f11.x;
        enc[2*l+1] = w00*f00.y + w10*f10.y + w01*f01.y + w11*f11.y;
    }

    // ---- MLP layer 1: 32 -> 64, relu. Weights are wave-uniform -> s_load. ----
    float h1[HIDDEN];
    #pragma unroll
    for (int j = 0; j < HIDDEN; ++j) h1[j] = b1[j];
    #pragma unroll
    for (int i = 0; i < 2 * NLEV; ++i) {
        #pragma unroll
        for (int j = 0; j < HIDDEN; ++j)
            h1[j] = fmaf(enc[i], W1[i * HIDDEN + j], h1[j]);
    }
    #pragma unroll
    for (int j = 0; j < HIDDEN; ++j) h1[j] = fmaxf(h1[j], 0.0f);

    // ---- MLP layer 2: 64 -> 64, relu ----
    float h2[HIDDEN];
    #pragma unroll
    for (int j = 0; j < HIDDEN; ++j) h2[j] = b2[j];
    #pragma unroll
    for (int i = 0; i < HIDDEN; ++i) {
        #pragma unroll
        for (int j = 0; j < HIDDEN; ++j)
            h2[j] = fmaf(h1[i], W2[i * HIDDEN + j], h2[j]);
    }
    #pragma unroll
    for (int j = 0; j < HIDDEN; ++j) h2[j] = fmaxf(h2[j], 0.0f);

    // ---- MLP layer 3: 64 -> 3, sigmoid, planar store ----
    float o0 = b3[0], o1 = b3[1], o2 = b3[2];
    #pragma unroll
    for (int i = 0; i < HIDDEN; ++i) {
        o0 = fmaf(h2[i], W3[i * 3 + 0], o0);
        o1 = fmaf(h2[i], W3[i * 3 + 1], o1);
        o2 = fmaf(h2[i], W3[i * 3 + 2], o2);
    }
    const int pix = (y << 10) | x;
    out[0 * NPIX + pix] = 1.0f / (1.0f + __expf(-o0));
    out[1 * NPIX + pix] = 1.0f / (1.0f + __expf(-o1));
    out[2 * NPIX + pix] = 1.0f / (1.0f + __expf(-o2));
}

extern "C" void kernel_launch(void* const* d_in, const int* in_sizes, int n_in,
                              void* d_out, int out_size, void* d_ws, size_t ws_size,
                              hipStream_t stream) {
    const float* tables = (const float*)d_in[0];
    const float* W1     = (const float*)d_in[1];
    const float* b1     = (const float*)d_in[2];
    const float* W2     = (const float*)d_in[3];
    const float* b2     = (const float*)d_in[4];
    const float* W3     = (const float*)d_in[5];
    const float* b3     = (const float*)d_in[6];
    float* out          = (float*)d_out;

    // res[l] = floor(16 * growth^l), growth = exp((ln 1024 - ln 16)/15), in f64
    // to match the numpy reference's boundary behavior.
    ResArr res;
    const double growth = exp((log(1024.0) - log(16.0)) / 15.0);
    for (int l = 0; l < NLEV; ++l)
        res.r[l] = (float)floor(16.0 * pow(growth, (double)l));

    dim3 grid(1024 / 32, 1024 / 8);
    dim3 block(256);
    hipLaunchKernelGGL(ngp_fused_kernel, grid, block, 0, stream,
                       tables, W1, b1, W2, b2, W3, b3, out, res);
}

// Round 2
// 91.127 us; speedup vs baseline: 2.5040x; 2.5040x over previous
//
#include <hip/hip_runtime.h>
#include <math.h>

#define NLEV   16
#define TSIZE  524288
#define TMASK  524287
#define HIDDEN 64
#define NPIX   (1024*1024)
#define LDS_STRIDE 72   // bf16 per pixel row (64 + 8 pad)

typedef __attribute__((ext_vector_type(8))) short s8v;
typedef __attribute__((ext_vector_type(4))) float f4v;

struct ResArr { float r[NLEV]; };
union Frag { unsigned int u[4]; s8v v; };

__device__ __forceinline__ unsigned short bf16_rn(float x) {
    unsigned int u = __builtin_bit_cast(unsigned int, x);
    u += 0x7fffu + ((u >> 16) & 1u);
    return (unsigned short)(u >> 16);
}
__device__ __forceinline__ unsigned int pk_bf16(float lo, float hi) {
    unsigned int a = __builtin_bit_cast(unsigned int, lo);
    unsigned int b = __builtin_bit_cast(unsigned int, hi);
    a += 0x7fffu + ((a >> 16) & 1u);
    b += 0x7fffu + ((b >> 16) & 1u);
    return (a >> 16) | (b & 0xffff0000u);
}

// ws layout (float offsets): [0..15] res f32; [16..271] W3 padded [64][4] f32;
// then at float offset 272: W1^T bf16 [64][32] (2048 ushort), W2^T bf16 [64][64] (4096 ushort)
__global__ __launch_bounds__(256) void prep_kernel(
    const float* __restrict__ W1, const float* __restrict__ W2,
    const float* __restrict__ W3, float* __restrict__ ws, ResArr res)
{
    const int t = threadIdx.x;
    if (t < NLEV) ws[t] = res.r[t];
    float* w3p = ws + 16;
    unsigned short* w1t = (unsigned short*)(ws + 272);
    unsigned short* w2t = w1t + 64 * 32;
    for (int i = t; i < 64 * 4; i += 256) {
        int r = i >> 2, c = i & 3;
        w3p[i] = (c < 3) ? W3[r * 3 + c] : 0.0f;
    }
    for (int i = t; i < 64 * 32; i += 256) {
        int n = i >> 5, k = i & 31;
        w1t[i] = bf16_rn(W1[k * 64 + n]);
    }
    for (int i = t; i < 64 * 64; i += 256) {
        int n = i >> 6, k = i & 63;
        w2t[i] = bf16_rn(W2[k * 64 + n]);
    }
}

// Block = 256 threads = 4 independent waves. Wave w handles image row y = by*4+w,
// x in [bx*64, bx*64+64). Lane l: c15 = l&15 (pixel-in-tile), g = l>>4 (k-group).
// Lane encodes levels g*4+j (j=0..3) for pixels pt*16+c15 (pt=0..3) -> B-fragments.
// Both MLP GEMMs computed transposed: D'[hidden][px] = W^T * enc^T.
__global__ __launch_bounds__(256) void ngp_mfma_kernel(
    const float* __restrict__ tables,
    const float* __restrict__ b1, const float* __restrict__ b2,
    const float* __restrict__ b3,
    const float* __restrict__ ws, float* __restrict__ out)
{
    __shared__ unsigned short h1lds[4][64 * LDS_STRIDE];  // 36864 B

    const int tid  = threadIdx.x;
    const int lane = tid & 63;
    const int wv   = tid >> 6;
    const int c15  = lane & 15;
    const int g    = lane >> 4;
    const int y    = blockIdx.y * 4 + wv;
    const int xb   = blockIdx.x * 64;

    // this lane's 4 level resolutions
    const float4 rv = *(const float4*)(ws + g * 4);
    const float rr[4] = { rv.x, rv.y, rv.z, rv.w };
    const float uy = (float)y * (1.0f / 1024.0f);
    const float2* __restrict__ tabg = (const float2*)tables + (size_t)(g * 4) * TSIZE;

    // ---- encode -> B-fragments (k = 2*level: pair (feat0,feat1) at u[j]) ----
    Frag bfrag[4];
    #pragma unroll
    for (int j = 0; j < 4; ++j) {
        const float r  = rr[j];
        const float sy = uy * r;
        const float fy0 = floorf(sy);
        const float fy  = sy - fy0;
        const unsigned int cy  = (unsigned int)fy0;
        const unsigned int hy0 = cy * 2654435761u;
        const unsigned int hy1 = hy0 + 2654435761u;
        const float2* __restrict__ tab = tabg + (size_t)j * TSIZE;
        #pragma unroll
        for (int pt = 0; pt < 4; ++pt) {
            const int x = xb + pt * 16 + c15;
            const float sx  = (float)x * (1.0f / 1024.0f) * r;
            const float fx0 = floorf(sx);
            const float fx  = sx - fx0;
            const unsigned int cx = (unsigned int)fx0;
            const unsigned int i00 = ( cx       ^ hy0) & TMASK;
            const unsigned int i10 = ((cx + 1u) ^ hy0) & TMASK;
            const unsigned int i01 = ( cx       ^ hy1) & TMASK;
            const unsigned int i11 = ((cx + 1u) ^ hy1) & TMASK;
            const float2 f00 = tab[i00];
            const float2 f10 = tab[i10];
            const float2 f01 = tab[i01];
            const float2 f11 = tab[i11];
            const float w00 = (1.0f - fx) * (1.0f - fy);
            const float w10 = fx          * (1.0f - fy);
            const float w01 = (1.0f - fx) * fy;
            const float w11 = fx          * fy;
            const float e0 = w00 * f00.x + w10 * f10.x + w01 * f01.x + w11 * f11.x;
            const float e1 = w00 * f00.y + w10 * f10.y + w01 * f01.y + w11 * f11.y;
            bfrag[pt].u[j] = pk_bf16(e0, e1);
        }
    }

    // ---- layer 1: D1'[n][px] = W1^T(64x32) * enc^T(32x64), K=32 (1 step) ----
    const unsigned short* __restrict__ w1t = (const unsigned short*)(ws + 272);
    const unsigned short* __restrict__ w2t = w1t + 64 * 32;
    Frag afr[4];
    #pragma unroll
    for (int mt = 0; mt < 4; ++mt)
        afr[mt].v = *(const s8v*)(w1t + (mt * 16 + c15) * 32 + g * 8);

    f4v acc1[4][4];
    #pragma unroll
    for (int mt = 0; mt < 4; ++mt)
        #pragma unroll
        for (int pt = 0; pt < 4; ++pt)
            acc1[mt][pt] = (f4v){0.f, 0.f, 0.f, 0.f};
    #pragma unroll
    for (int mt = 0; mt < 4; ++mt)
        #pragma unroll
        for (int pt = 0; pt < 4; ++pt)
            acc1[mt][pt] = __builtin_amdgcn_mfma_f32_16x16x32_bf16(
                afr[mt].v, bfrag[pt].v, acc1[mt][pt], 0, 0, 0);

    // ---- bias + relu + pack -> per-wave LDS h1[px][n] bf16 ----
    unsigned short* __restrict__ hl = &h1lds[wv][0];
    #pragma unroll
    for (int mt = 0; mt < 4; ++mt) {
        const float4 bb = *(const float4*)(b1 + mt * 16 + g * 4);
        #pragma unroll
        for (int pt = 0; pt < 4; ++pt) {
            const f4v v = acc1[mt][pt];
            const float v0 = fmaxf(v[0] + bb.x, 0.0f);
            const float v1 = fmaxf(v[1] + bb.y, 0.0f);
            const float v2 = fmaxf(v[2] + bb.z, 0.0f);
            const float v3 = fmaxf(v[3] + bb.w, 0.0f);
            // n = mt*16 + g*4 + {0..3}, px = pt*16 + c15
            unsigned int* dst = (unsigned int*)(hl + (pt * 16 + c15) * LDS_STRIDE + mt * 16 + g * 4);
            dst[0] = pk_bf16(v0, v1);
            dst[1] = pk_bf16(v2, v3);
        }
    }

    // ---- layer 2: D2'[n2][px] = W2^T(64x64) * h1^T(64x64), K=64 (2 steps) ----
    f4v acc2[4][4];
    #pragma unroll
    for (int mt = 0; mt < 4; ++mt)
        #pragma unroll
        for (int pt = 0; pt < 4; ++pt)
            acc2[mt][pt] = (f4v){0.f, 0.f, 0.f, 0.f};
    #pragma unroll
    for (int st = 0; st < 2; ++st) {
        Frag a2[4], bf2[4];
        #pragma unroll
        for (int mt = 0; mt < 4; ++mt)
            a2[mt].v = *(const s8v*)(w2t + (mt * 16 + c15) * 64 + st * 32 + g * 8);
        #pragma unroll
        for (int pt = 0; pt < 4; ++pt)
            bf2[pt].v = *(const s8v*)(hl + (pt * 16 + c15) * LDS_STRIDE + st * 32 + g * 8);
        #pragma unroll
        for (int mt = 0; mt < 4; ++mt)
            #pragma unroll
            for (int pt = 0; pt < 4; ++pt)
                acc2[mt][pt] = __builtin_amdgcn_mfma_f32_16x16x32_bf16(
                    a2[mt].v, bf2[pt].v, acc2[mt][pt], 0, 0, 0);
    }

    // ---- bias + relu, layer 3 (64 -> 3) on VALU, butterfly over g ----
    const float* __restrict__ w3p = ws + 16;
    float part[4][3] = {{0,0,0},{0,0,0},{0,0,0},{0,0,0}};
    #pragma unroll
    for (int mt = 0; mt < 4; ++mt) {
        const float4 bb2 = *(const float4*)(b2 + mt * 16 + g * 4);
        const float bbv[4] = { bb2.x, bb2.y, bb2.z, bb2.w };
        #pragma unroll
        for (int r = 0; r < 4; ++r) {
            const float4 w3 = *(const float4*)(w3p + (size_t)(mt * 16 + g * 4 + r) * 4);
            #pragma unroll
            for (int pt = 0; pt < 4; ++pt) {
                const float h = fmaxf(acc2[mt][pt][r] + bbv[r], 0.0f);
                part[pt][0] = fmaf(h, w3.x, part[pt][0]);
                part[pt][1] = fmaf(h, w3.y, part[pt][1]);
                part[pt][2] = fmaf(h, w3.z, part[pt][2]);
            }
        }
    }
    #pragma unroll
    for (int pt = 0; pt < 4; ++pt)
        #pragma unroll
        for (int c = 0; c < 3; ++c) {
            float v = part[pt][c];
            v += __shfl_xor(v, 16);
            v += __shfl_xor(v, 32);
            part[pt][c] = v;
        }
    // lane-group g stores pixel chunk pt == g (256 B contiguous per store)
    float o0 = 0.f, o1 = 0.f, o2 = 0.f;
    #pragma unroll
    for (int pt = 0; pt < 4; ++pt) {
        if (g == pt) { o0 = part[pt][0]; o1 = part[pt][1]; o2 = part[pt][2]; }
    }
    o0 += b3[0]; o1 += b3[1]; o2 += b3[2];
    const int pix = (y << 10) + xb + g * 16 + c15;
    out[0 * NPIX + pix] = 1.0f / (1.0f + __expf(-o0));
    out[1 * NPIX + pix] = 1.0f / (1.0f + __expf(-o1));
    out[2 * NPIX + pix] = 1.0f / (1.0f + __expf(-o2));
}

extern "C" void kernel_launch(void* const* d_in, const int* in_sizes, int n_in,
                              void* d_out, int out_size, void* d_ws, size_t ws_size,
                              hipStream_t stream) {
    const float* tables = (const float*)d_in[0];
    const float* W1     = (const float*)d_in[1];
    const float* b1     = (const float*)d_in[2];
    const float* W2     = (const float*)d_in[3];
    const float* b2     = (const float*)d_in[4];
    const float* W3     = (const float*)d_in[5];
    const float* b3     = (const float*)d_in[6];
    float* out          = (float*)d_out;
    float* ws           = (float*)d_ws;

    ResArr res;
    const double growth = exp((log(1024.0) - log(16.0)) / 15.0);
    for (int l = 0; l < NLEV; ++l)
        res.r[l] = (float)floor(16.0 * pow(growth, (double)l));

    hipLaunchKernelGGL(prep_kernel, dim3(1), dim3(256), 0, stream, W1, W2, W3, ws, res);
    hipLaunchKernelGGL(ngp_mfma_kernel, dim3(16, 256), dim3(256), 0, stream,
                       tables, b1, b2, b3, ws, out);
}

// Round 3
// 85.363 us; speedup vs baseline: 2.6730x; 1.0675x over previous
//
#include <hip/hip_runtime.h>
#include <math.h>

#define NLEV   16
#define TSIZE  524288
#define TMASK  524287
#define NPIX   (1024*1024)

typedef __attribute__((ext_vector_type(8))) short s8v;
typedef __attribute__((ext_vector_type(4))) float f4v;

struct ResArr { float r[NLEV]; };
union Frag { unsigned int u[4]; s8v v; };

__device__ __forceinline__ unsigned short bf16_rn(float x) {
    unsigned int u = __builtin_bit_cast(unsigned int, x);
    u += 0x7fffu + ((u >> 16) & 1u);
    return (unsigned short)(u >> 16);
}
__device__ __forceinline__ unsigned int pk_bf16(float lo, float hi) {
    unsigned int a = __builtin_bit_cast(unsigned int, lo);
    unsigned int b = __builtin_bit_cast(unsigned int, hi);
    a += 0x7fffu + ((a >> 16) & 1u);
    b += 0x7fffu + ((b >> 16) & 1u);
    return (a >> 16) | (b & 0xffff0000u);
}

// ws layout (float offsets): [0..15] res f32; [16..271] W3 padded [64][4] f32;
// at float offset 272: W1^T bf16 [64][32] (2048 ushort), then W2^T bf16 [64][64].
__global__ __launch_bounds__(256) void prep_kernel(
    const float* __restrict__ W1, const float* __restrict__ W2,
    const float* __restrict__ W3, float* __restrict__ ws, ResArr res)
{
    const int t = threadIdx.x;
    if (t < NLEV) ws[t] = res.r[t];
    float* w3p = ws + 16;
    unsigned short* w1t = (unsigned short*)(ws + 272);
    unsigned short* w2t = w1t + 64 * 32;
    for (int i = t; i < 64 * 4; i += 256) {
        int r = i >> 2, c = i & 3;
        w3p[i] = (c < 3) ? W3[r * 3 + c] : 0.0f;
    }
    for (int i = t; i < 64 * 32; i += 256) {
        int n = i >> 5, k = i & 31;
        w1t[i] = bf16_rn(W1[k * 64 + n]);
    }
    for (int i = t; i < 64 * 64; i += 256) {
        int n = i >> 6, k = i & 63;
        w2t[i] = bf16_rn(W2[k * 64 + n]);
    }
}

// Block = 4 independent waves; wave -> image row y = by*4+wv, x in [bx*64, bx*64+64).
// Lane (c15 = l&15, g = l>>4): encodes levels g*4+j for pixels pt*16+c15 -> B-frags.
// MLP GEMMs in swapped form D' = W^T * act^T on mfma_f32_16x16x32_bf16.
// h1 round-trip through per-wave LDS, XOR-swizzled (word ^= (c15&7)<<2):
// conflict-optimal for both b64 writes and b128 reads.
__global__ __launch_bounds__(256, 5) void ngp_mfma_kernel(
    const float* __restrict__ tables,
    const float* __restrict__ b1, const float* __restrict__ b2,
    const float* __restrict__ b3,
    const float* __restrict__ ws, float* __restrict__ out)
{
    __shared__ unsigned int h1lds[4][2048];   // 8 KiB per wave, 32 KiB total

    const int tid  = threadIdx.x;
    const int lane = tid & 63;
    const int wv   = tid >> 6;
    const int c15  = lane & 15;
    const int g    = lane >> 4;
    const int a7   = c15 & 7;
    const int y    = blockIdx.y * 4 + wv;
    const int xb   = blockIdx.x * 64;

    const float4 rv = *(const float4*)(ws + g * 4);
    const float rr[4] = { rv.x, rv.y, rv.z, rv.w };
    const float uy = (float)y * (1.0f / 1024.0f);
    float xf[4];
    #pragma unroll
    for (int pt = 0; pt < 4; ++pt)
        xf[pt] = (float)(xb + pt * 16 + c15) * (1.0f / 1024.0f);

    const float2* __restrict__ tabg = (const float2*)tables + (size_t)(g * 4) * TSIZE;

    // ---- encode: per level j, issue all 16 gathers, then consume ----
    Frag bfrag[4];
    #pragma unroll
    for (int j = 0; j < 4; ++j) {
        const float r  = rr[j];
        const float sy = uy * r;
        const float fy0 = floorf(sy);
        const float fy  = sy - fy0;
        const unsigned int cy  = (unsigned int)fy0;
        const unsigned int hy0 = cy * 2654435761u;
        const unsigned int hy1 = hy0 + 2654435761u;
        const float2* __restrict__ tab = tabg + (size_t)j * TSIZE;
        float2 f[4][4];
        float fxv[4];
        #pragma unroll
        for (int pt = 0; pt < 4; ++pt) {
            const float sx  = xf[pt] * r;
            const float fx0 = floorf(sx);
            fxv[pt] = sx - fx0;
            const unsigned int cx = (unsigned int)fx0;
            f[pt][0] = tab[( cx        ^ hy0) & TMASK];
            f[pt][1] = tab[((cx + 1u)  ^ hy0) & TMASK];
            f[pt][2] = tab[( cx        ^ hy1) & TMASK];
            f[pt][3] = tab[((cx + 1u)  ^ hy1) & TMASK];
        }
        #pragma unroll
        for (int pt = 0; pt < 4; ++pt) {
            const float fx  = fxv[pt];
            const float w00 = (1.0f - fx) * (1.0f - fy);
            const float w10 = fx          * (1.0f - fy);
            const float w01 = (1.0f - fx) * fy;
            const float w11 = fx          * fy;
            const float e0 = w00 * f[pt][0].x + w10 * f[pt][1].x
                           + w01 * f[pt][2].x + w11 * f[pt][3].x;
            const float e1 = w00 * f[pt][0].y + w10 * f[pt][1].y
                           + w01 * f[pt][2].y + w11 * f[pt][3].y;
            bfrag[pt].u[j] = pk_bf16(e0, e1);
        }
    }

    // ---- layer 1: D1'[n][px] = W1^T(64x32) * enc^T(32x64), K=32 ----
    const unsigned short* __restrict__ w1t = (const unsigned short*)(ws + 272);
    const unsigned short* __restrict__ w2t = w1t + 64 * 32;
    Frag afr[4];
    #pragma unroll
    for (int mt = 0; mt < 4; ++mt)
        afr[mt].v = *(const s8v*)(w1t + (mt * 16 + c15) * 32 + g * 8);

    f4v acc1[4][4];
    #pragma unroll
    for (int mt = 0; mt < 4; ++mt)
        #pragma unroll
        for (int pt = 0; pt < 4; ++pt)
            acc1[mt][pt] = (f4v){0.f, 0.f, 0.f, 0.f};
    #pragma unroll
    for (int mt = 0; mt < 4; ++mt)
        #pragma unroll
        for (int pt = 0; pt < 4; ++pt)
            acc1[mt][pt] = __builtin_amdgcn_mfma_f32_16x16x32_bf16(
                afr[mt].v, bfrag[pt].v, acc1[mt][pt], 0, 0, 0);

    // ---- bias + relu + pack -> per-wave swizzled LDS (logical h1[px][n]) ----
    unsigned int* __restrict__ hw = &h1lds[wv][0];
    #pragma unroll
    for (int mt = 0; mt < 4; ++mt) {
        const float4 bb = *(const float4*)(b1 + mt * 16 + g * 4);
        #pragma unroll
        for (int pt = 0; pt < 4; ++pt) {
            const f4v v = acc1[mt][pt];
            const float v0 = fmaxf(v[0] + bb.x, 0.0f);
            const float v1 = fmaxf(v[1] + bb.y, 0.0f);
            const float v2 = fmaxf(v[2] + bb.z, 0.0f);
            const float v3 = fmaxf(v[3] + bb.w, 0.0f);
            // logical words (mt*8+g*2)+{0,1} of pixel pt*16+c15
            unsigned int* dst = hw + ((pt * 16 + c15) << 5)
                                   + ((mt * 8 + g * 2) ^ (a7 << 2));
            dst[0] = pk_bf16(v0, v1);
            dst[1] = pk_bf16(v2, v3);
        }
    }

    // ---- layer 2: D2'[n2][px] = W2^T(64x64) * h1^T(64x64), K=64 ----
    f4v acc2[4][4];
    #pragma unroll
    for (int mt = 0; mt < 4; ++mt)
        #pragma unroll
        for (int pt = 0; pt < 4; ++pt)
            acc2[mt][pt] = (f4v){0.f, 0.f, 0.f, 0.f};
    #pragma unroll
    for (int st = 0; st < 2; ++st) {
        Frag a2[4], bf2[4];
        #pragma unroll
        for (int mt = 0; mt < 4; ++mt)
            a2[mt].v = *(const s8v*)(w2t + (mt * 16 + c15) * 64 + st * 32 + g * 8);
        #pragma unroll
        for (int pt = 0; pt < 4; ++pt)
            bf2[pt].v = *(const s8v*)(hw + ((pt * 16 + c15) << 5)
                                         + ((st * 16 + g * 4) ^ (a7 << 2)));
        #pragma unroll
        for (int mt = 0; mt < 4; ++mt)
            #pragma unroll
            for (int pt = 0; pt < 4; ++pt)
                acc2[mt][pt] = __builtin_amdgcn_mfma_f32_16x16x32_bf16(
                    a2[mt].v, bf2[pt].v, acc2[mt][pt], 0, 0, 0);
    }

    // ---- bias + relu, layer 3 (64 -> 3) on VALU, butterfly over g ----
    const float* __restrict__ w3p = ws + 16;
    float part[4][3] = {{0,0,0},{0,0,0},{0,0,0},{0,0,0}};
    #pragma unroll
    for (int mt = 0; mt < 4; ++mt) {
        const float4 bb2 = *(const float4*)(b2 + mt * 16 + g * 4);
        const float bbv[4] = { bb2.x, bb2.y, bb2.z, bb2.w };
        #pragma unroll
        for (int r = 0; r < 4; ++r) {
            const float4 w3 = *(const float4*)(w3p + (size_t)(mt * 16 + g * 4 + r) * 4);
            #pragma unroll
            for (int pt = 0; pt < 4; ++pt) {
                const float h = fmaxf(acc2[mt][pt][r] + bbv[r], 0.0f);
                part[pt][0] = fmaf(h, w3.x, part[pt][0]);
                part[pt][1] = fmaf(h, w3.y, part[pt][1]);
                part[pt][2] = fmaf(h, w3.z, part[pt][2]);
            }
        }
    }
    #pragma unroll
    for (int pt = 0; pt < 4; ++pt)
        #pragma unroll
        for (int c = 0; c < 3; ++c) {
            float v = part[pt][c];
            v += __shfl_xor(v, 16);
            v += __shfl_xor(v, 32);
            part[pt][c] = v;
        }
    float o0 = 0.f, o1 = 0.f, o2 = 0.f;
    #pragma unroll
    for (int pt = 0; pt < 4; ++pt) {
        if (g == pt) { o0 = part[pt][0]; o1 = part[pt][1]; o2 = part[pt][2]; }
    }
    o0 += b3[0]; o1 += b3[1]; o2 += b3[2];
    const int pix = (y << 10) + xb + g * 16 + c15;
    out[0 * NPIX + pix] = 1.0f / (1.0f + __expf(-o0));
    out[1 * NPIX + pix] = 1.0f / (1.0f + __expf(-o1));
    out[2 * NPIX + pix] = 1.0f / (1.0f + __expf(-o2));
}

extern "C" void kernel_launch(void* const* d_in, const int* in_sizes, int n_in,
                              void* d_out, int out_size, void* d_ws, size_t ws_size,
                              hipStream_t stream) {
    const float* tables = (const float*)d_in[0];
    const float* W1     = (const float*)d_in[1];
    const float* b1     = (const float*)d_in[2];
    const float* W2     = (const float*)d_in[3];
    const float* b2     = (const float*)d_in[4];
    const float* W3     = (const float*)d_in[5];
    const float* b3     = (const float*)d_in[6];
    float* out          = (float*)d_out;
    float* ws           = (float*)d_ws;

    ResArr res;
    const double growth = exp((log(1024.0) - log(16.0)) / 15.0);
    for (int l = 0; l < NLEV; ++l)
        res.r[l] = (float)floor(16.0 * pow(growth, (double)l));

    hipLaunchKernelGGL(prep_kernel, dim3(1), dim3(256), 0, stream, W1, W2, W3, ws, res);
    hipLaunchKernelGGL(ngp_mfma_kernel, dim3(16, 256), dim3(256), 0, stream,
                       tables, b1, b2, b3, ws, out);
}

// Round 4
// 71.874 us; speedup vs baseline: 3.1747x; 1.1877x over previous
//
#include <hip/hip_runtime.h>
#include <math.h>

#define NLEV   16
#define TSIZE  524288
#define TMASK  524287
#define NPIX   (1024*1024)

typedef __attribute__((ext_vector_type(8))) short s8v;
typedef __attribute__((ext_vector_type(4))) float f4v;

struct ResArr { float r[NLEV]; };
union Frag { unsigned int u[4]; s8v v; };

__device__ __forceinline__ unsigned short bf16_rn(float x) {
    unsigned int u = __builtin_bit_cast(unsigned int, x);
    u += 0x7fffu + ((u >> 16) & 1u);
    return (unsigned short)(u >> 16);
}
// truncating bf16 pack: one v_perm_b32. |rel err| <= 2^-8, values ~1e-4,
// output threshold 1e-2 -> negligible.
__device__ __forceinline__ unsigned int pk_bf16(float lo, float hi) {
    return __builtin_amdgcn_perm(__builtin_bit_cast(unsigned int, hi),
                                 __builtin_bit_cast(unsigned int, lo),
                                 0x07060302u);
}

// ws layout (float offsets): [0..15] res f32; [16..271] W3 padded [64][4] f32;
// at float offset 272: W1^T bf16 [64][32] (2048 ushort), then W2^T bf16 [64][64].
__global__ __launch_bounds__(256) void prep_kernel(
    const float* __restrict__ W1, const float* __restrict__ W2,
    const float* __restrict__ W3, float* __restrict__ ws, ResArr res)
{
    const int t = threadIdx.x;
    if (t < NLEV) ws[t] = res.r[t];
    float* w3p = ws + 16;
    unsigned short* w1t = (unsigned short*)(ws + 272);
    unsigned short* w2t = w1t + 64 * 32;
    for (int i = t; i < 64 * 4; i += 256) {
        int r = i >> 2, c = i & 3;
        w3p[i] = (c < 3) ? W3[r * 3 + c] : 0.0f;
    }
    for (int i = t; i < 64 * 32; i += 256) {
        int n = i >> 5, k = i & 31;
        w1t[i] = bf16_rn(W1[k * 64 + n]);
    }
    for (int i = t; i < 64 * 64; i += 256) {
        int n = i >> 6, k = i & 63;
        w2t[i] = bf16_rn(W2[k * 64 + n]);
    }
}

// Block = 4 waves covering a 16x16 pixel tile; wave wv owns rows wv*4..wv*4+3.
// Lane (c15 = l&15, g = l>>4). Logical GEMM pixel px = pt*16 + c15 maps to
// spatial (x = xb + c15, y = yb + wv*4 + pt): 16x4 tile -> ~2.5x fewer cache
// lines per gather batch than a 64x1 strip, stores stay 64B-coalesced.
// MLP GEMMs in swapped form D' = W^T * act^T on mfma_f32_16x16x32_bf16;
// h1 round-trip through per-wave XOR-swizzled LDS.
__global__ __launch_bounds__(256, 4) void ngp_mfma_kernel(
    const float* __restrict__ tables,
    const float* __restrict__ b1, const float* __restrict__ b2,
    const float* __restrict__ b3,
    const float* __restrict__ ws, float* __restrict__ out)
{
    __shared__ unsigned int h1lds[4][2048];   // 8 KiB per wave, 32 KiB total

    const int tid  = threadIdx.x;
    const int lane = tid & 63;
    const int wv   = tid >> 6;
    const int c15  = lane & 15;
    const int g    = lane >> 4;
    const int a7   = c15 & 7;
    const int xb   = blockIdx.x * 16;
    const int yb   = blockIdx.y * 16;

    const float4 rv = *(const float4*)(ws + g * 4);
    const float rr[4] = { rv.x, rv.y, rv.z, rv.w };
    const float xs = (float)(xb + c15) * (1.0f / 1024.0f);
    float yf[4];
    #pragma unroll
    for (int pt = 0; pt < 4; ++pt)
        yf[pt] = (float)(yb + wv * 4 + pt) * (1.0f / 1024.0f);

    const float2* __restrict__ tabg = (const float2*)tables + (size_t)(g * 4) * TSIZE;

    // ---- encode: per level j, issue all 16 gathers, then consume ----
    Frag bfrag[4];
    #pragma unroll
    for (int j = 0; j < 4; ++j) {
        const float r  = rr[j];
        const float sx = xs * r;
        const float fx0 = floorf(sx);
        const float fx  = sx - fx0;
        const unsigned int cx  = (unsigned int)fx0;
        const unsigned int cx1 = cx + 1u;
        const float2* __restrict__ tab = tabg + (size_t)j * TSIZE;
        float2 f[4][4];
        float fyv[4];
        #pragma unroll
        for (int pt = 0; pt < 4; ++pt) {
            const float sy  = yf[pt] * r;
            const float fy0 = floorf(sy);
            fyv[pt] = sy - fy0;
            const unsigned int cy  = (unsigned int)fy0;
            const unsigned int hy0 = cy * 2654435761u;
            const unsigned int hy1 = hy0 + 2654435761u;
            f[pt][0] = tab[(cx  ^ hy0) & TMASK];
            f[pt][1] = tab[(cx1 ^ hy0) & TMASK];
            f[pt][2] = tab[(cx  ^ hy1) & TMASK];
            f[pt][3] = tab[(cx1 ^ hy1) & TMASK];
        }
        #pragma unroll
        for (int pt = 0; pt < 4; ++pt) {
            const float fy  = fyv[pt];
            const float w00 = (1.0f - fx) * (1.0f - fy);
            const float w10 = fx          * (1.0f - fy);
            const float w01 = (1.0f - fx) * fy;
            const float w11 = fx          * fy;
            const float e0 = w00 * f[pt][0].x + w10 * f[pt][1].x
                           + w01 * f[pt][2].x + w11 * f[pt][3].x;
            const float e1 = w00 * f[pt][0].y + w10 * f[pt][1].y
                           + w01 * f[pt][2].y + w11 * f[pt][3].y;
            bfrag[pt].u[j] = pk_bf16(e0, e1);
        }
    }

    // ---- layer 1: D1'[n][px] = W1^T(64x32) * enc^T(32x64), K=32 ----
    const unsigned short* __restrict__ w1t = (const unsigned short*)(ws + 272);
    const unsigned short* __restrict__ w2t = w1t + 64 * 32;
    Frag afr[4];
    #pragma unroll
    for (int mt = 0; mt < 4; ++mt)
        afr[mt].v = *(const s8v*)(w1t + (mt * 16 + c15) * 32 + g * 8);

    f4v acc1[4][4];
    #pragma unroll
    for (int mt = 0; mt < 4; ++mt)
        #pragma unroll
        for (int pt = 0; pt < 4; ++pt)
            acc1[mt][pt] = (f4v){0.f, 0.f, 0.f, 0.f};
    #pragma unroll
    for (int mt = 0; mt < 4; ++mt)
        #pragma unroll
        for (int pt = 0; pt < 4; ++pt)
            acc1[mt][pt] = __builtin_amdgcn_mfma_f32_16x16x32_bf16(
                afr[mt].v, bfrag[pt].v, acc1[mt][pt], 0, 0, 0);

    // ---- bias + relu + pack -> per-wave swizzled LDS (logical h1[px][n]) ----
    unsigned int* __restrict__ hw = &h1lds[wv][0];
    #pragma unroll
    for (int mt = 0; mt < 4; ++mt) {
        const float4 bb = *(const float4*)(b1 + mt * 16 + g * 4);
        #pragma unroll
        for (int pt = 0; pt < 4; ++pt) {
            const f4v v = acc1[mt][pt];
            const float v0 = fmaxf(v[0] + bb.x, 0.0f);
            const float v1 = fmaxf(v[1] + bb.y, 0.0f);
            const float v2 = fmaxf(v[2] + bb.z, 0.0f);
            const float v3 = fmaxf(v[3] + bb.w, 0.0f);
            unsigned int* dst = hw + ((pt * 16 + c15) << 5)
                                   + ((mt * 8 + g * 2) ^ (a7 << 2));
            dst[0] = pk_bf16(v0, v1);
            dst[1] = pk_bf16(v2, v3);
        }
    }

    // ---- layer 2: D2'[n2][px] = W2^T(64x64) * h1^T(64x64), K=64 ----
    f4v acc2[4][4];
    #pragma unroll
    for (int mt = 0; mt < 4; ++mt)
        #pragma unroll
        for (int pt = 0; pt < 4; ++pt)
            acc2[mt][pt] = (f4v){0.f, 0.f, 0.f, 0.f};
    #pragma unroll
    for (int st = 0; st < 2; ++st) {
        Frag a2[4], bf2[4];
        #pragma unroll
        for (int mt = 0; mt < 4; ++mt)
            a2[mt].v = *(const s8v*)(w2t + (mt * 16 + c15) * 64 + st * 32 + g * 8);
        #pragma unroll
        for (int pt = 0; pt < 4; ++pt)
            bf2[pt].v = *(const s8v*)(hw + ((pt * 16 + c15) << 5)
                                         + ((st * 16 + g * 4) ^ (a7 << 2)));
        #pragma unroll
        for (int mt = 0; mt < 4; ++mt)
            #pragma unroll
            for (int pt = 0; pt < 4; ++pt)
                acc2[mt][pt] = __builtin_amdgcn_mfma_f32_16x16x32_bf16(
                    a2[mt].v, bf2[pt].v, acc2[mt][pt], 0, 0, 0);
    }

    // ---- bias + relu, layer 3 (64 -> 3) on VALU, butterfly over g ----
    const float* __restrict__ w3p = ws + 16;
    float part[4][3] = {{0,0,0},{0,0,0},{0,0,0},{0,0,0}};
    #pragma unroll
    for (int mt = 0; mt < 4; ++mt) {
        const float4 bb2 = *(const float4*)(b2 + mt * 16 + g * 4);
        const float bbv[4] = { bb2.x, bb2.y, bb2.z, bb2.w };
        #pragma unroll
        for (int r = 0; r < 4; ++r) {
            const float4 w3 = *(const float4*)(w3p + (size_t)(mt * 16 + g * 4 + r) * 4);
            #pragma unroll
            for (int pt = 0; pt < 4; ++pt) {
                const float h = fmaxf(acc2[mt][pt][r] + bbv[r], 0.0f);
                part[pt][0] = fmaf(h, w3.x, part[pt][0]);
                part[pt][1] = fmaf(h, w3.y, part[pt][1]);
                part[pt][2] = fmaf(h, w3.z, part[pt][2]);
            }
        }
    }
    #pragma unroll
    for (int pt = 0; pt < 4; ++pt)
        #pragma unroll
        for (int c = 0; c < 3; ++c) {
            float v = part[pt][c];
            v += __shfl_xor(v, 16);
            v += __shfl_xor(v, 32);
            part[pt][c] = v;
        }
    float o0 = 0.f, o1 = 0.f, o2 = 0.f;
    #pragma unroll
    for (int pt = 0; pt < 4; ++pt) {
        if (g == pt) { o0 = part[pt][0]; o1 = part[pt][1]; o2 = part[pt][2]; }
    }
    o0 += b3[0]; o1 += b3[1]; o2 += b3[2];
    const int pix = ((yb + wv * 4 + g) << 10) + xb + c15;
    out[0 * NPIX + pix] = 1.0f / (1.0f + __expf(-o0));
    out[1 * NPIX + pix] = 1.0f / (1.0f + __expf(-o1));
    out[2 * NPIX + pix] = 1.0f / (1.0f + __expf(-o2));
}

extern "C" void kernel_launch(void* const* d_in, const int* in_sizes, int n_in,
                              void* d_out, int out_size, void* d_ws, size_t ws_size,
                              hipStream_t stream) {
    const float* tables = (const float*)d_in[0];
    const float* W1     = (const float*)d_in[1];
    const float* b1     = (const float*)d_in[2];
    const float* W2     = (const float*)d_in[3];
    const float* b2     = (const float*)d_in[4];
    const float* W3     = (const float*)d_in[5];
    const float* b3     = (const float*)d_in[6];
    float* out          = (float*)d_out;
    float* ws           = (float*)d_ws;

    ResArr res;
    const double growth = exp((log(1024.0) - log(16.0)) / 15.0);
    for (int l = 0; l < NLEV; ++l)
        res.r[l] = (float)floor(16.0 * pow(growth, (double)l));

    hipLaunchKernelGGL(prep_kernel, dim3(1), dim3(256), 0, stream, W1, W2, W3, ws, res);
    hipLaunchKernelGGL(ngp_mfma_kernel, dim3(64, 64), dim3(256), 0, stream,
                       tables, b1, b2, b3, ws, out);
}